// Round 10
// baseline (130.850 us; speedup 1.0000x reference)
//
#include <hip/hip_runtime.h>

#define NUM_NODES   120000
#define NUM_MOVABLE 100000
#define NUM_NETS    100000
#define NUM_PINS    400000
#define NBX 256
#define NBY 256
#define GRID_BINS (NBX*NBY)
#define NSB 391             // scatter blocks = ceil(NUM_NETS/256); also #segments/row
#define SEGCAP 32           // per-(row,block) segment capacity (max expected ~18)

constexpr float BSX      = 1000.0f / 256.0f;   // 3.90625 exact in binary
constexpr float INV_BS   = 256.0f / 1000.0f;
constexpr float BIN_AREA = BSX * BSX;
constexpr float EPSV     = 1e-6f;

// Workspace layout (elements):
//   cnt_rb: u32[256*NSB]        per-(row,segment) entry counts (plain stores)
//   entries:float4[256*NSB*SEGCAP]  SELF-CONTAINED corner records:
//           {x_corner, ymn, ymx, ±coef_v}; sign bit of .w encodes side
//           (0 = low-x corner, 1 = high-x corner). No bbox array at all —
//           splat reads are fully coalesced, no random gathers.
//   A_hT,B_hT,A_vT,B_vT: float[GRID_BINS] transposed [y*NBX+x]
//   util:   float[GRID_BINS]    [x*NBY+y]
// H(x,y) = A_h(x,y) + sum_{x'<x} B_h(x',y); same for V.

// ------------------------------------------------------- bbox + scatter
// One thread per net: serial pin loop (independent iterations -> pipelined
// gathers), then private-segment scatter of two self-contained corner
// records via LDS cursors. NO global atomics, NO bbox array.
__global__ void bbox_scatter(const float* __restrict__ pin_pos,
                             const int* __restrict__ netpin_start,
                             const int* __restrict__ flat_netpin,
                             unsigned* __restrict__ cnt_rb,
                             float4* __restrict__ entries) {
    __shared__ unsigned cur[256];
    int tid = threadIdx.x, blk = blockIdx.x;
    if (tid < 256) cur[tid] = 0u;
    __syncthreads();
    int n = blk * 256 + tid;
    if (n < NUM_NETS) {
        int s = netpin_start[n], e = netpin_start[n + 1];
        if (e > s) {
            float xmn = 3.4e38f, xmx = -3.4e38f, ymn = 3.4e38f, ymx = -3.4e38f;
            for (int i = s; i < e; ++i) {
                int p = flat_netpin[i];
                float px = pin_pos[p];
                float py = pin_pos[NUM_PINS + p];
                xmn = fminf(xmn, px); xmx = fmaxf(xmx, px);
                ymn = fminf(ymn, py); ymx = fmaxf(ymx, py);
            }
            float span_x = xmx - xmn, span_y = ymx - ymn;
            if (span_y > EPSV || span_x > EPSV) {
                float coef_v = (span_x > EPSV) ? 1.0f / span_x : 0.0f;
                unsigned bxl = (unsigned)min((int)(xmn * INV_BS), NBX - 1);
                unsigned bxh = (unsigned)min((int)(xmx * INV_BS), NBX - 1);
                // side encoded in sign bit of .w (exact, handles coef_v==0)
                float cv_hi = __uint_as_float(__float_as_uint(coef_v) | 0x80000000u);
                unsigned p0 = atomicAdd(&cur[bxl], 1u);
                if (p0 < SEGCAP)
                    entries[(bxl * NSB + blk) * SEGCAP + p0] =
                        make_float4(xmn, ymn, ymx, coef_v);
                unsigned p1 = atomicAdd(&cur[bxh], 1u);
                if (p1 < SEGCAP)
                    entries[(bxh * NSB + blk) * SEGCAP + p1] =
                        make_float4(xmx, ymn, ymx, cv_hi);
            }
        }
    }
    __syncthreads();
    if (tid < 256) cnt_rb[tid * NSB + blk] = min(cur[tid], (unsigned)SEGCAP);
}

// ---------------------------------------------------------------- splat phase
// One block per bx row; parallel 512-wide inclusive scan of its NSB segment
// counts, then walks the ~780 row entries — all reads coalesced.
// LDS accumulation, in-block y-scan, transposed A/B emit. No global atomics.
__global__ __launch_bounds__(1024) void splat_rows(
        const unsigned* __restrict__ cnt_rb,
        const float4* __restrict__ entries,
        float* __restrict__ A_hT, float* __restrict__ B_hT,
        float* __restrict__ A_vT, float* __restrict__ B_vT) {
    int bx = blockIdx.x;
    int t  = threadIdx.x;
    __shared__ float    F[8][NBY];  // 0 P_h, 1 CX_h, 2 CY_h, 3 Q_h, 4..7 same V
    __shared__ unsigned S[512];     // inclusive segment-count prefix
    for (int i = t; i < 8 * NBY; i += 1024) ((float*)F)[i] = 0.0f;
    if (t < 512) S[t] = (t < NSB) ? cnt_rb[bx * NSB + t] : 0u;
    __syncthreads();
    for (int d = 1; d < 512; d <<= 1) {
        unsigned add = 0u;
        if (t < 512 && t >= d) add = S[t - d];
        __syncthreads();
        if (t < 512) S[t] += add;
        __syncthreads();
    }
    int total = (int)S[NSB - 1];

    for (int j = t; j < total; j += 1024) {
        // segment = upper_bound over inclusive prefix S
        int lo = 0, hi = NSB;
        while (lo < hi) {
            int mid = (lo + hi) >> 1;
            if ((int)S[mid] <= j) lo = mid + 1; else hi = mid;
        }
        int off = j - (lo > 0 ? (int)S[lo - 1] : 0);
        float4 e = entries[(bx * NSB + lo) * SEGCAP + off];
        // decode: x corner, ymn, ymx, ±coef_v (sign = side)
        float x    = e.x;
        float ymn  = e.y, ymx = e.z;
        bool  side = (__float_as_uint(e.w) >> 31) != 0u;
        float coef_v = fabsf(e.w);
        float span_y = ymx - ymn;
        float coef_h = (span_y > EPSV) ? 1.0f / span_y : 0.0f;
        float s0 = side ? -1.0f : 1.0f;
        float rx = (float)(bx + 1) * BSX - x;   // row == corner's bin (incl. clamp)
        int byl = min((int)(ymn * INV_BS), NBY - 1);
        int byh = min((int)(ymx * INV_BS), NBY - 1);
        float ryl = (float)(byl + 1) * BSX - ymn;
        float ryh = (float)(byh + 1) * BSX - ymx;
        if (coef_h != 0.0f) {
            float w0 = s0 * coef_h, w1 = -s0 * coef_h;
            atomicAdd(&F[0][byl], w0 * rx  * ryl);
            atomicAdd(&F[1][byl], w0 * rx  * BSX);
            atomicAdd(&F[2][byl], w0 * BSX * ryl);
            atomicAdd(&F[3][byl], w0 * BSX * BSX);
            atomicAdd(&F[0][byh], w1 * rx  * ryh);
            atomicAdd(&F[1][byh], w1 * rx  * BSX);
            atomicAdd(&F[2][byh], w1 * BSX * ryh);
            atomicAdd(&F[3][byh], w1 * BSX * BSX);
        }
        if (coef_v != 0.0f) {
            float w0 = s0 * coef_v, w1 = -s0 * coef_v;
            atomicAdd(&F[4][byl], w0 * rx  * ryl);
            atomicAdd(&F[5][byl], w0 * rx  * BSX);
            atomicAdd(&F[6][byl], w0 * BSX * ryl);
            atomicAdd(&F[7][byl], w0 * BSX * BSX);
            atomicAdd(&F[4][byh], w1 * rx  * ryh);
            atomicAdd(&F[5][byh], w1 * rx  * BSX);
            atomicAdd(&F[6][byh], w1 * BSX * ryh);
            atomicAdd(&F[7][byh], w1 * BSX * BSX);
        }
    }
    __syncthreads();

    // In-block inclusive y-scan of fields 1,3,5,7 (CX_h, Q_h, CX_v, Q_v).
    int g = t >> 8, y = t & 255;
    float* f = F[2 * g + 1];
    for (int d = 1; d < 256; d <<= 1) {
        float add = (y >= d) ? f[y - d] : 0.0f;
        __syncthreads();
        f[y] += add;
        __syncthreads();
    }
    // A = P + exclusive(CX); B = CY + exclusive(Q). Emit transposed.
    float ex  = (y > 0) ? F[2 * g + 1][y - 1] : 0.0f;
    float val = F[2 * g][y] + ex;
    float* o  = (g == 0) ? A_hT : (g == 1) ? B_hT : (g == 2) ? A_vT : B_vT;
    o[y * NBX + bx] = val;
}

// ---------------------------------------------------------------- x-scan+util
// One block per y, thread per x. Coalesced reads from transposed arrays.
__global__ void scan_x_util(const float* __restrict__ A_hT, const float* __restrict__ B_hT,
                            const float* __restrict__ A_vT, const float* __restrict__ B_vT,
                            float* __restrict__ util) {
    int y = blockIdx.x, x = threadIdx.x;
    int idxT = y * NBX + x;
    __shared__ float2 tmp[NBX];
    tmp[x] = make_float2(B_hT[idxT], B_vT[idxT]);
    __syncthreads();
    for (int d = 1; d < 256; d <<= 1) {
        float2 add = (x >= d) ? tmp[x - d] : make_float2(0.f, 0.f);
        __syncthreads();
        tmp[x].x += add.x; tmp[x].y += add.y;
        __syncthreads();
    }
    float2 ex = (x > 0) ? tmp[x - 1] : make_float2(0.f, 0.f);
    float H = A_hT[idxT] + ex.x;
    float V = A_vT[idxT] + ex.y;
    float u = fmaxf(H, V) * (1.0f / (BIN_AREA * 1.5f));
    util[x * NBY + y] = fminf(fmaxf(u, 0.5f), 2.0f);
}

// ---------------------------------------------------------------- node phase
__global__ void node_area(const float* __restrict__ pos,
                          const float* __restrict__ nsx,
                          const float* __restrict__ nsy,
                          const float* __restrict__ util,
                          float* __restrict__ out) {
    int m = blockIdx.x * 256 + threadIdx.x;
    if (m >= NUM_MOVABLE) return;
    float xl = pos[m];
    float yl = pos[NUM_NODES + m];
    float xh = xl + nsx[m];
    float yh = yl + nsy[m];
    int bx0 = max(0, min((int)(xl * INV_BS), NBX - 1));
    int bx1 = max(0, min((int)(xh * INV_BS), NBX - 1));
    int by0 = max(0, min((int)(yl * INV_BS), NBY - 1));
    int by1 = max(0, min((int)(yh * INV_BS), NBY - 1));
    float acc = 0.0f;
    for (int bx = bx0; bx <= bx1; ++bx) {
        float ox = fminf(xh, (float)(bx + 1) * BSX) - fmaxf(xl, (float)bx * BSX);
        if (ox <= 0.0f) continue;
        const float* urow = util + bx * NBY;
        float inner = 0.0f;
        for (int by = by0; by <= by1; ++by) {
            float oy = fminf(yh, (float)(by + 1) * BSX) - fmaxf(yl, (float)by * BSX);
            if (oy > 0.0f) inner += oy * urow[by];
        }
        acc += ox * inner;
    }
    out[m] = acc;
}

extern "C" void kernel_launch(void* const* d_in, const int* in_sizes, int n_in,
                              void* d_out, int out_size, void* d_ws, size_t ws_size,
                              hipStream_t stream) {
    const float* pos          = (const float*)d_in[0];
    const float* pin_pos      = (const float*)d_in[1];
    const float* node_size_x  = (const float*)d_in[2];
    const float* node_size_y  = (const float*)d_in[3];
    const int*   netpin_start = (const int*)d_in[4];
    const int*   flat_netpin  = (const int*)d_in[5];

    unsigned* cnt_rb  = (unsigned*)d_ws;                        // 400 KB
    float4*   entries = (float4*)(cnt_rb + 256 * NSB);          // 51.2 MB
    float*    A_hT    = (float*)(entries + 256 * NSB * SEGCAP); // 4 x 256 KB
    float*    B_hT    = A_hT + GRID_BINS;
    float*    A_vT    = B_hT + GRID_BINS;
    float*    B_vT    = A_vT + GRID_BINS;
    float*    util    = B_vT + GRID_BINS;                       // 256 KB
    float*    out     = (float*)d_out;

    bbox_scatter<<<NSB, 256, 0, stream>>>(
        pin_pos, netpin_start, flat_netpin, cnt_rb, entries);
    splat_rows<<<NBX, 1024, 0, stream>>>(cnt_rb, entries,
                                         A_hT, B_hT, A_vT, B_vT);
    scan_x_util<<<NBY, NBX, 0, stream>>>(A_hT, B_hT, A_vT, B_vT, util);
    node_area<<<(NUM_MOVABLE + 255) / 256, 256, 0, stream>>>(
        pos, node_size_x, node_size_y, util, out);
}